// Round 2
// baseline (628.750 us; speedup 1.0000x reference)
//
#include <hip/hip_runtime.h>

#define N_EDGES   640000
#define NODE_DIM  128
#define EDGE_DIM  64
#define K_DIM     192
#define LDS_K     196   // pad 192->196 shorts: row stride 98 dwords == 2 mod 32 -> 2-way LDS conflict (free)
#define GRID      1000
#define WPB       4
#define ITERS     (N_EDGES / 32 / (GRID * WPB))   // 5

typedef float  f32x16 __attribute__((ext_vector_type(16)));
typedef __bf16 bf16x8 __attribute__((ext_vector_type(8)));

union FragU {
  uint   u[4];
  bf16x8 b;
};

__device__ __forceinline__ ushort f2bf_rne(float f) {
  uint u = __builtin_bit_cast(uint, f);
  return (ushort)((u + 0x7fffu + ((u >> 16) & 1u)) >> 16);
}

__device__ __forceinline__ uint pack2bf(float f0, float f1) {
  uint u0 = __builtin_bit_cast(uint, f0) + 0x8000u;
  uint u1 = __builtin_bit_cast(uint, f1) + 0x8000u;
  return __builtin_amdgcn_perm(u1, u0, 0x07060302u);
}

// One-time prep: W [192][128] fp32 row-major -> WTg bf16 transposed+padded [128][196]
__global__ __launch_bounds__(256) void prep_w(const float* __restrict__ W,
                                              ushort* __restrict__ WTg) {
  int i = blockIdx.x * 256 + threadIdx.x;
  if (i >= K_DIM * NODE_DIM) return;
  int k = i >> 7, n = i & 127;
  WTg[n * LDS_K + k] = f2bf_rne(W[i]);
}

__global__ __launch_bounds__(256, 3) void a2b_main(
    const float* __restrict__ atom, const float* __restrict__ edgef,
    const int* __restrict__ srcidx, const ushort* __restrict__ WTg,
    const float* __restrict__ bias, float* __restrict__ out) {
  __shared__ ushort WT[NODE_DIM * LDS_K];  // 50176 B -> 3 blocks/CU by LDS

  {  // coalesced 50 KB copy of pre-converted W (L2-resident after first block)
    const uint4* s4 = (const uint4*)WTg;
    uint4* d4 = (uint4*)WT;
#pragma unroll
    for (int i = 0; i < 12; i++) d4[threadIdx.x + i * 256] = s4[threadIdx.x + i * 256];
    int r = 3072 + threadIdx.x;
    if (r < 3136) d4[r] = s4[r];
  }
  __syncthreads();

  const int wave = threadIdx.x >> 6;
  const int lane = threadIdx.x & 63;
  const int eloc = lane & 31;
  const int half = lane >> 5;

  float bb[4];
#pragma unroll
  for (int nt = 0; nt < 4; nt++) bb[nt] = bias[nt * 32 + eloc];

  const int gw = blockIdx.x * WPB + wave;  // 0..3999
  int e = gw * 32 + eloc;
  int s = srcidx[e];

  for (int it = 0; it < ITERS; ++it) {
    const int ebase = e - eloc;
    const float* arow = atom  + (size_t)s * NODE_DIM;
    const float* erow = edgef + (size_t)e * EDGE_DIM;

    // A-frag (32x32x16): lane holds A[m=eloc][k = ks*16 + half*8 + j]
    // Gather+pack in 4 phases of 3 ks (6 float4 in flight per phase) to cap VGPRs.
    uint aF[12][4];
#pragma unroll
    for (int ph = 0; ph < 4; ++ph) {
      float4 v[3][2];
#pragma unroll
      for (int j = 0; j < 3; ++j) {
        const int ks = ph * 3 + j;
        const int k0 = ks * 16 + half * 8;
        const float* p = (ks < 8) ? (arow + k0) : (erow + (k0 - 128));
        v[j][0] = *(const float4*)p;
        v[j][1] = *(const float4*)(p + 4);
      }
#pragma unroll
      for (int j = 0; j < 3; ++j) {
        const int ks = ph * 3 + j;
        aF[ks][0] = pack2bf(v[j][0].x, v[j][0].y);
        aF[ks][1] = pack2bf(v[j][0].z, v[j][0].w);
        aF[ks][2] = pack2bf(v[j][1].x, v[j][1].y);
        aF[ks][3] = pack2bf(v[j][1].z, v[j][1].w);
      }
    }

    // prefetch next tile's source index (hides idx->gather dependency)
    const int e_next = e + GRID * WPB * 32;
    int s_next = 0;
    if (it + 1 < ITERS) s_next = srcidx[e_next];

    f32x16 acc[4];
#pragma unroll
    for (int nt = 0; nt < 4; nt++)
#pragma unroll
      for (int i = 0; i < 16; i++) acc[nt][i] = 0.f;

#pragma unroll
    for (int ks = 0; ks < 12; ks++) {
      FragU a;
      a.u[0] = aF[ks][0]; a.u[1] = aF[ks][1];
      a.u[2] = aF[ks][2]; a.u[3] = aF[ks][3];
      const int kof = ks * 16 + half * 8;
#pragma unroll
      for (int nt = 0; nt < 4; nt++) {
        // B-frag: B[k=kof+j][n=nt*32+eloc] = WT[n][kof+j], 16 B contiguous, 8-B aligned
        const uint2* bp = (const uint2*)&WT[(nt * 32 + eloc) * LDS_K + kof];
        uint2 b0 = bp[0], b1 = bp[1];
        FragU bf_;
        bf_.u[0] = b0.x; bf_.u[1] = b0.y; bf_.u[2] = b1.x; bf_.u[3] = b1.y;
        acc[nt] = __builtin_amdgcn_mfma_f32_32x32x16_bf16(a.b, bf_.b, acc[nt], 0, 0, 0);
      }
    }

    // C/D (32x32): col = lane&31, row = (reg&3) + 8*(reg>>2) + 4*(lane>>5)
#pragma unroll
    for (int nt = 0; nt < 4; nt++) {
      const int col = nt * 32 + eloc;
#pragma unroll
      for (int r = 0; r < 16; r++) {
        const int row = (r & 3) + 8 * (r >> 2) + 4 * half;
        out[(size_t)(ebase + row) * NODE_DIM + col] = fmaxf(acc[nt][r] + bb[nt], 0.f);
      }
    }

    e = e_next;
    s = s_next;
  }
}

extern "C" void kernel_launch(void* const* d_in, const int* in_sizes, int n_in,
                              void* d_out, int out_size, void* d_ws, size_t ws_size,
                              hipStream_t stream) {
  const float* atom   = (const float*)d_in[0];
  const float* edgef  = (const float*)d_in[1];
  const int*   srcidx = (const int*)d_in[2];
  const float* W      = (const float*)d_in[3];
  const float* bias   = (const float*)d_in[4];
  float* out   = (float*)d_out;
  ushort* WTg  = (ushort*)d_ws;  // 128*196*2 = 50176 B

  hipLaunchKernelGGL(prep_w, dim3(96), dim3(256), 0, stream, W, WTg);
  hipLaunchKernelGGL(a2b_main, dim3(GRID), dim3(256), 0, stream,
                     atom, edgef, srcidx, WTg, bias, out);
}